// Round 1
// baseline (490.481 us; speedup 1.0000x reference)
//
#include <hip/hip_runtime.h>
#include <hip/hip_bf16.h>

// Problem: B=512, T=256, C=384, H=64 single-head causal attention.
// inputs: x [B,T,C] f32, Wq/Wk/Wv [C,H] f32. output: [B,T,H] f32.
// Round 0: correctness baseline.
//   kernel 1: fp32 tiled GEMM -> q,k,v stored bf16 in workspace (50 MB)
//   kernel 2: per-batch flash-style attention, k/v in LDS (bf16, 64 KB)

constexpr int BSZ  = 512;
constexpr int TT   = 256;
constexpr int CDIM = 384;
constexpr int HDIM = 64;
constexpr long long BT = (long long)BSZ * TT;      // 131072 rows
constexpr float SCALE = 0.051031036307982884f;     // 384^-0.5 (note: C, not H)

__device__ inline void unpack2(unsigned int u, float &a, float &b) {
    a = __uint_as_float(u << 16);
    b = __uint_as_float(u & 0xFFFF0000u);
}
__device__ inline void unpack8(uint4 u, float* e) {
    unpack2(u.x, e[0], e[1]);
    unpack2(u.y, e[2], e[3]);
    unpack2(u.z, e[4], e[5]);
    unpack2(u.w, e[6], e[7]);
}

// ---------------- kernel 1: QKV projection GEMM ----------------
// grid (BT/64, 3), block 256. Each block: 64x64 output tile of one of q/k/v.
// A = x [BT x 384] f32, B = W [384 x 64] f32, C -> ws bf16 [3][BT][64].
__global__ __launch_bounds__(256) void qkv_gemm(
    const float* __restrict__ x,
    const float* __restrict__ Wq,
    const float* __restrict__ Wk,
    const float* __restrict__ Wv,
    unsigned short* __restrict__ ws)
{
    __shared__ __align__(16) float As[32][64];   // [k][m]
    __shared__ __align__(16) float Bs[32][64];   // [k][n]

    const int tid = threadIdx.x;
    const int m0  = blockIdx.x * 64;
    const float* W = (blockIdx.y == 0) ? Wq : (blockIdx.y == 1) ? Wk : Wv;
    unsigned short* outp = ws + (size_t)blockIdx.y * BT * HDIM;

    const int tm = (tid >> 4) * 4;   // 0..60
    const int tn = (tid & 15) * 4;   // 0..60
    float acc[4][4] = {};

    for (int k0 = 0; k0 < CDIM; k0 += 32) {
        // stage A tile: 64 rows x 32 k, 2048 floats = 256 thr x 2 float4
        #pragma unroll
        for (int p = 0; p < 2; ++p) {
            int e  = p * 1024 + tid * 4;
            int m  = e >> 5;          // 0..63
            int kk = e & 31;          // multiple of 4
            float4 v4 = *(const float4*)&x[(size_t)(m0 + m) * CDIM + k0 + kk];
            As[kk + 0][m] = v4.x;
            As[kk + 1][m] = v4.y;
            As[kk + 2][m] = v4.z;
            As[kk + 3][m] = v4.w;
        }
        // stage B tile: 32 k x 64 n
        #pragma unroll
        for (int p = 0; p < 2; ++p) {
            int e  = p * 1024 + tid * 4;
            int kk = e >> 6;          // 0..31
            int n  = e & 63;          // multiple of 4
            *(float4*)&Bs[kk][n] = *(const float4*)&W[(size_t)(k0 + kk) * HDIM + n];
        }
        __syncthreads();
        #pragma unroll
        for (int k = 0; k < 32; ++k) {
            float4 a4 = *(const float4*)&As[k][tm];
            float4 b4 = *(const float4*)&Bs[k][tn];
            float a[4] = {a4.x, a4.y, a4.z, a4.w};
            float b[4] = {b4.x, b4.y, b4.z, b4.w};
            #pragma unroll
            for (int i = 0; i < 4; ++i)
                #pragma unroll
                for (int j = 0; j < 4; ++j)
                    acc[i][j] += a[i] * b[j];
        }
        __syncthreads();
    }

    #pragma unroll
    for (int i = 0; i < 4; ++i) {
        unsigned short pk[4];
        #pragma unroll
        for (int j = 0; j < 4; ++j) {
            __hip_bfloat16 h = __float2bfloat16(acc[i][j]);
            pk[j] = *(unsigned short*)&h;
        }
        *(uint2*)&outp[(size_t)(m0 + tm + i) * HDIM + tn] = *(uint2*)pk;
    }
}

// ---------------- kernel 2: causal attention, one block per batch ----------------
// block = 256 threads, thread t owns q-row t. k,v staged in LDS as bf16 (64 KB).
// Online softmax (rescale only on new max), fp32 accumulate.
__global__ __launch_bounds__(256) void attn(
    const unsigned short* __restrict__ ws, float* __restrict__ out)
{
    __shared__ __align__(16) unsigned short ks[TT * HDIM];  // 32 KB
    __shared__ __align__(16) unsigned short vs[TT * HDIM];  // 32 KB

    const int b = blockIdx.x;
    const int t = threadIdx.x;

    const unsigned short* qg = ws;
    const unsigned short* kg = ws + (size_t)1 * BT * HDIM;
    const unsigned short* vg = ws + (size_t)2 * BT * HDIM;

    // stage k,v for this batch: 2048 uint4 each
    const uint4* ksrc = (const uint4*)(kg + (size_t)b * TT * HDIM);
    const uint4* vsrc = (const uint4*)(vg + (size_t)b * TT * HDIM);
    uint4* kdst = (uint4*)ks;
    uint4* vdst = (uint4*)vs;
    for (int i = t; i < TT * HDIM / 8; i += 256) {
        kdst[i] = ksrc[i];
        vdst[i] = vsrc[i];
    }

    // q row -> fp32 registers
    float qf[64];
    {
        const uint4* qrow = (const uint4*)(qg + ((size_t)b * TT + t) * HDIM);
        #pragma unroll
        for (int i = 0; i < 8; ++i) { uint4 u = qrow[i]; unpack8(u, &qf[i * 8]); }
    }
    __syncthreads();

    float m = -INFINITY, l = 0.f;
    float o[64];
    #pragma unroll
    for (int h = 0; h < 64; ++h) o[h] = 0.f;

    for (int s = 0; s <= t; ++s) {
        const uint4* kr = (const uint4*)&ks[s * HDIM];
        float sc = 0.f;
        #pragma unroll
        for (int i = 0; i < 8; ++i) {
            float e[8]; unpack8(kr[i], e);
            #pragma unroll
            for (int j = 0; j < 8; ++j) sc += qf[i * 8 + j] * e[j];
        }
        sc *= SCALE;
        if (sc > m) {                     // rare after first few iters
            float corr = __expf(m - sc);  // exp(-inf)=0 on first iter
            l *= corr;
            #pragma unroll
            for (int h = 0; h < 64; ++h) o[h] *= corr;
            m = sc;
        }
        float p = __expf(sc - m);
        l += p;
        const uint4* vr = (const uint4*)&vs[s * HDIM];
        #pragma unroll
        for (int i = 0; i < 8; ++i) {
            float e[8]; unpack8(vr[i], e);
            #pragma unroll
            for (int j = 0; j < 8; ++j) o[i * 8 + j] += p * e[j];
        }
    }

    const float inv = 1.f / l;
    float* orow = out + ((size_t)b * TT + t) * HDIM;
    #pragma unroll
    for (int i = 0; i < 16; ++i) {
        float4 w4;
        w4.x = o[i * 4 + 0] * inv;
        w4.y = o[i * 4 + 1] * inv;
        w4.z = o[i * 4 + 2] * inv;
        w4.w = o[i * 4 + 3] * inv;
        *(float4*)&orow[i * 4] = w4;
    }
}

extern "C" void kernel_launch(void* const* d_in, const int* in_sizes, int n_in,
                              void* d_out, int out_size, void* d_ws, size_t ws_size,
                              hipStream_t stream)
{
    const float* x  = (const float*)d_in[0];
    const float* Wq = (const float*)d_in[1];
    const float* Wk = (const float*)d_in[2];
    const float* Wv = (const float*)d_in[3];
    unsigned short* ws = (unsigned short*)d_ws;   // bf16 q|k|v, 3*131072*64*2 = 50.3 MB
    float* out = (float*)d_out;

    dim3 g1(BT / 64, 3);
    qkv_gemm<<<g1, 256, 0, stream>>>(x, Wq, Wk, Wv, ws);
    attn<<<BSZ, 256, 0, stream>>>(ws, out);
}

// Round 2
// 285.817 us; speedup vs baseline: 1.7161x; 1.7161x over previous
//
#include <hip/hip_runtime.h>
#include <hip/hip_bf16.h>

// B=512, T=256, C=384, H=64 single-head causal attention.
// Round 1: QKV projection -> fused bf16 MFMA GEMM (M=131072, N=192, K=384).
//   prep_bt : W -> Bt[192][384] bf16 (transposed, stored in d_out scratch area)
//   qkv_gemm: x fp32 -> LDS bf16, MFMA 16x16x32, qkv interleaved [BT][192] bf16 in ws
//   attn    : unchanged flash-style per-batch kernel (MFMA rewrite next round)

constexpr int BSZ  = 512;
constexpr int TT   = 256;
constexpr int CDIM = 384;
constexpr int HDIM = 64;
constexpr int NQKV = 192;                      // q|k|v concatenated
constexpr long long BT = (long long)BSZ * TT;  // 131072 rows
constexpr float SCALE = 0.051031036307982884f; // 384^-0.5 (C, not head size)

typedef __attribute__((ext_vector_type(8))) short bf16x8;
typedef __attribute__((ext_vector_type(4))) float f32x4;

__device__ inline unsigned short f2bf(float f) {
    __hip_bfloat16 h = __float2bfloat16(f);
    return *(unsigned short*)&h;
}
__device__ inline void unpack2(unsigned int u, float &a, float &b) {
    a = __uint_as_float(u << 16);
    b = __uint_as_float(u & 0xFFFF0000u);
}
__device__ inline void unpack8(uint4 u, float* e) {
    unpack2(u.x, e[0], e[1]);
    unpack2(u.y, e[2], e[3]);
    unpack2(u.z, e[4], e[5]);
    unpack2(u.w, e[6], e[7]);
}

// ---------------- kernel 0: build Bt[192][384] bf16 = [Wq|Wk|Wv]^T ----------------
__global__ __launch_bounds__(256) void prep_bt(
    const float* __restrict__ Wq, const float* __restrict__ Wk,
    const float* __restrict__ Wv, unsigned short* __restrict__ bt)
{
    int idx = blockIdx.x * 256 + threadIdx.x;
    if (idx >= NQKV * CDIM) return;
    int n = idx / CDIM, k = idx - n * CDIM;
    const float* W = (n < 64) ? Wq : (n < 128) ? Wk : Wv;
    bt[idx] = f2bf(W[(size_t)k * HDIM + (n & 63)]);
}

// ---------------- kernel 1: fused QKV MFMA GEMM ----------------
// grid 2048 (M/64), block 256 (4 waves). Block tile 64x192, wave tile 64x48.
constexpr int AS_STRIDE = 392;  // shorts/row: 384 + 8 pad -> 784 B == 4 banks mod 32
constexpr int OS_STRIDE = 200;  // epilogue staging stride (400 B == 4 banks mod 32)

__global__ __launch_bounds__(256) void qkv_gemm(
    const float* __restrict__ x, const unsigned short* __restrict__ bt,
    unsigned short* __restrict__ qkv)
{
    __shared__ __align__(16) unsigned short lds[64 * AS_STRIDE];  // 50176 B

    const int tid = threadIdx.x;
    const int m0  = blockIdx.x * 64;

    // ---- stage A: 64 rows x 384 fp32 -> bf16 LDS (rows contiguous in x) ----
    const float4* xs = (const float4*)(x + (size_t)m0 * CDIM);
    #pragma unroll
    for (int p = 0; p < 24; ++p) {
        int i = p * 256 + tid;            // 6144 float4 total
        float4 v = xs[i];
        int row = i / 96, c4 = i - row * 96;
        unsigned short pk[4] = { f2bf(v.x), f2bf(v.y), f2bf(v.z), f2bf(v.w) };
        *(uint2*)&lds[row * AS_STRIDE + c4 * 4] = *(uint2*)pk;
    }
    __syncthreads();

    // ---- MFMA main loop ----
    const int wave = tid >> 6;
    const int lane = tid & 63;
    const int lr   = lane & 15;   // row (A) / col (B,D) within 16-tile
    const int lk   = lane >> 4;   // k-chunk 0..3 (8 contiguous bf16 each)
    const int n0   = wave * 48;   // wave's 48-col slice of N=192

    f32x4 acc[4][3];
    #pragma unroll
    for (int mi = 0; mi < 4; ++mi)
        #pragma unroll
        for (int ni = 0; ni < 3; ++ni)
            acc[mi][ni] = (f32x4){0.f, 0.f, 0.f, 0.f};

    for (int ks = 0; ks < 12; ++ks) {     // K = 384 = 12 x 32
        bf16x8 a[4], b[3];
        #pragma unroll
        for (int mi = 0; mi < 4; ++mi)
            a[mi] = *(const bf16x8*)&lds[(mi * 16 + lr) * AS_STRIDE + ks * 32 + lk * 8];
        #pragma unroll
        for (int ni = 0; ni < 3; ++ni)
            b[ni] = *(const bf16x8*)&bt[(size_t)(n0 + ni * 16 + lr) * CDIM + ks * 32 + lk * 8];
        #pragma unroll
        for (int mi = 0; mi < 4; ++mi)
            #pragma unroll
            for (int ni = 0; ni < 3; ++ni)
                acc[mi][ni] = __builtin_amdgcn_mfma_f32_16x16x32_bf16(
                    a[mi], b[ni], acc[mi][ni], 0, 0, 0);
    }
    __syncthreads();  // done reading A tile; reuse lds for epilogue

    // ---- epilogue: acc -> LDS [64][192] (stride 200), then coalesced store ----
    #pragma unroll
    for (int mi = 0; mi < 4; ++mi) {
        #pragma unroll
        for (int ni = 0; ni < 3; ++ni) {
            int col = n0 + ni * 16 + lr;
            #pragma unroll
            for (int r = 0; r < 4; ++r) {
                int row = mi * 16 + lk * 4 + r;   // D: col=lane&15, row=(lane>>4)*4+r
                lds[row * OS_STRIDE + col] = f2bf(acc[mi][ni][r]);
            }
        }
    }
    __syncthreads();
    #pragma unroll
    for (int p = 0; p < 6; ++p) {
        int i = p * 256 + tid;                 // 1536 uint4 = 64 rows x 24
        int row = i / 24, c = i - row * 24;
        *(uint4*)&qkv[(size_t)(m0 + row) * NQKV + c * 8] =
            *(const uint4*)&lds[row * OS_STRIDE + c * 8];
    }
}

// ---------------- kernel 2: causal attention, one block per batch ----------------
// qkv rows are [q(64) | k(64) | v(64)] bf16. Unchanged math from round 0.
__global__ __launch_bounds__(256) void attn(
    const unsigned short* __restrict__ qkv, float* __restrict__ out)
{
    __shared__ __align__(16) unsigned short ks[TT * HDIM];  // 32 KB
    __shared__ __align__(16) unsigned short vs[TT * HDIM];  // 32 KB

    const int b = blockIdx.x;
    const int t = threadIdx.x;

    for (int i = t; i < TT * 8; i += 256) {   // 2048 uint4 per tensor
        int row = i >> 3, c = i & 7;
        const size_t rb = ((size_t)b * TT + row) * NQKV;
        ((uint4*)ks)[i] = *(const uint4*)&qkv[rb + HDIM + c * 8];
        ((uint4*)vs)[i] = *(const uint4*)&qkv[rb + 2 * HDIM + c * 8];
    }

    float qf[64];
    {
        const uint4* qrow = (const uint4*)&qkv[((size_t)b * TT + t) * NQKV];
        #pragma unroll
        for (int i = 0; i < 8; ++i) { uint4 u = qrow[i]; unpack8(u, &qf[i * 8]); }
    }
    __syncthreads();

    float m = -INFINITY, l = 0.f;
    float o[64];
    #pragma unroll
    for (int h = 0; h < 64; ++h) o[h] = 0.f;

    for (int s = 0; s <= t; ++s) {
        const uint4* kr = (const uint4*)&ks[s * HDIM];
        float sc = 0.f;
        #pragma unroll
        for (int i = 0; i < 8; ++i) {
            float e[8]; unpack8(kr[i], e);
            #pragma unroll
            for (int j = 0; j < 8; ++j) sc += qf[i * 8 + j] * e[j];
        }
        sc *= SCALE;
        if (sc > m) {
            float corr = __expf(m - sc);
            l *= corr;
            #pragma unroll
            for (int h = 0; h < 64; ++h) o[h] *= corr;
            m = sc;
        }
        float p = __expf(sc - m);
        l += p;
        const uint4* vr = (const uint4*)&vs[s * HDIM];
        #pragma unroll
        for (int i = 0; i < 8; ++i) {
            float e[8]; unpack8(vr[i], e);
            #pragma unroll
            for (int j = 0; j < 8; ++j) o[i * 8 + j] += p * e[j];
        }
    }

    const float inv = 1.f / l;
    float* orow = out + ((size_t)b * TT + t) * HDIM;
    #pragma unroll
    for (int i = 0; i < 16; ++i) {
        float4 w4;
        w4.x = o[i * 4 + 0] * inv;
        w4.y = o[i * 4 + 1] * inv;
        w4.z = o[i * 4 + 2] * inv;
        w4.w = o[i * 4 + 3] * inv;
        *(float4*)&orow[i * 4] = w4;
    }
}

extern "C" void kernel_launch(void* const* d_in, const int* in_sizes, int n_in,
                              void* d_out, int out_size, void* d_ws, size_t ws_size,
                              hipStream_t stream)
{
    const float* x  = (const float*)d_in[0];
    const float* Wq = (const float*)d_in[1];
    const float* Wk = (const float*)d_in[2];
    const float* Wv = (const float*)d_in[3];
    unsigned short* qkv = (unsigned short*)d_ws;       // [BT][192] bf16 = 50.3 MB
    // Bt lives at the start of d_out (33.5 MB fp32); attn fully overwrites d_out
    // afterwards, and we write Bt before reading it on every call (deterministic).
    unsigned short* bt  = (unsigned short*)d_out;      // [192][384] bf16 = 147 KB
    float* out = (float*)d_out;

    prep_bt<<<(NQKV * CDIM + 255) / 256, 256, 0, stream>>>(Wq, Wk, Wv, bt);
    qkv_gemm<<<BT / 64, 256, 0, stream>>>(x, bt, qkv);
    attn<<<BSZ, 256, 0, stream>>>(qkv, out);
}

// Round 3
// 115.466 us; speedup vs baseline: 4.2478x; 2.4753x over previous
//
#include <hip/hip_runtime.h>
#include <hip/hip_bf16.h>

// B=512, T=256, C=384, H=64 single-head causal attention.
// Round 2: MFMA flash attention.
//   prep_bt : W -> Bt[192][384] bf16 (in d_out scratch, overwritten later)
//   qkv_gemm: x -> q,k (interleaved [BT][128], q pre-scaled by 384^-0.5)
//             and vT [512][64][256] bf16, all in ws
//   attn    : per-batch, 4 waves, wave w owns q-strips {32w, 224-32w}
//             (balanced causal work: 5 strip x s-tile pairs per wave).
//             QK^T/PV via mfma 16x16x32; V^T LDS XOR-swizzled; P relayout
//             through wave-private swizzled LDS.

constexpr int BSZ  = 512;
constexpr int TT   = 256;
constexpr int CDIM = 384;
constexpr int HDIM = 64;
constexpr int NQKV = 192;
constexpr long long BT = (long long)BSZ * TT;   // 131072 rows
constexpr float SCALE = 0.051031036307982884f;  // 384^-0.5 (C, not head size)

typedef __attribute__((ext_vector_type(8))) short bf16x8;
typedef __attribute__((ext_vector_type(4))) float f32x4;

__device__ inline unsigned short f2bf(float f) {
    __hip_bfloat16 h = __float2bfloat16(f);
    return *(unsigned short*)&h;
}

// ---------------- kernel 0: Bt[192][384] bf16 = [Wq|Wk|Wv]^T ----------------
__global__ __launch_bounds__(256) void prep_bt(
    const float* __restrict__ Wq, const float* __restrict__ Wk,
    const float* __restrict__ Wv, unsigned short* __restrict__ bt)
{
    int idx = blockIdx.x * 256 + threadIdx.x;
    if (idx >= NQKV * CDIM) return;
    int n = idx / CDIM, k = idx - n * CDIM;
    const float* W = (n < 64) ? Wq : (n < 128) ? Wk : Wv;
    bt[idx] = f2bf(W[(size_t)k * HDIM + (n & 63)]);
}

// ---------------- kernel 1: fused QKV MFMA GEMM ----------------
constexpr int AS_STRIDE = 392;  // staging stride (784 B == 4 banks mod 32)
constexpr int OS_STRIDE = 200;  // epilogue stride (400 B; 16B-aligned rows)

__global__ __launch_bounds__(256) void qkv_gemm(
    const float* __restrict__ x, const unsigned short* __restrict__ bt,
    unsigned short* __restrict__ qk, unsigned short* __restrict__ vtg)
{
    __shared__ __align__(16) unsigned short lds[64 * AS_STRIDE];  // 50176 B

    const int tid = threadIdx.x;
    const int m0  = blockIdx.x * 64;

    // stage A: 64 rows x 384 fp32 -> bf16 LDS
    const float4* xs = (const float4*)(x + (size_t)m0 * CDIM);
    #pragma unroll
    for (int p = 0; p < 24; ++p) {
        int i = p * 256 + tid;
        float4 v = xs[i];
        int row = i / 96, c4 = i - row * 96;
        unsigned short pk[4] = { f2bf(v.x), f2bf(v.y), f2bf(v.z), f2bf(v.w) };
        *(uint2*)&lds[row * AS_STRIDE + c4 * 4] = *(uint2*)pk;
    }
    __syncthreads();

    const int wave = tid >> 6;
    const int lane = tid & 63;
    const int lr   = lane & 15;
    const int lk   = lane >> 4;
    const int n0   = wave * 48;

    f32x4 acc[4][3];
    #pragma unroll
    for (int mi = 0; mi < 4; ++mi)
        #pragma unroll
        for (int ni = 0; ni < 3; ++ni)
            acc[mi][ni] = (f32x4){0.f, 0.f, 0.f, 0.f};

    for (int ks = 0; ks < 12; ++ks) {
        bf16x8 a[4], bfr[3];
        #pragma unroll
        for (int mi = 0; mi < 4; ++mi)
            a[mi] = *(const bf16x8*)&lds[(mi * 16 + lr) * AS_STRIDE + ks * 32 + lk * 8];
        #pragma unroll
        for (int ni = 0; ni < 3; ++ni)
            bfr[ni] = *(const bf16x8*)&bt[(size_t)(n0 + ni * 16 + lr) * CDIM + ks * 32 + lk * 8];
        #pragma unroll
        for (int mi = 0; mi < 4; ++mi)
            #pragma unroll
            for (int ni = 0; ni < 3; ++ni)
                acc[mi][ni] = __builtin_amdgcn_mfma_f32_16x16x32_bf16(
                    a[mi], bfr[ni], acc[mi][ni], 0, 0, 0);
    }
    __syncthreads();

    // epilogue: acc -> LDS [64][192] stride 200; q cols pre-scaled by SCALE
    #pragma unroll
    for (int mi = 0; mi < 4; ++mi) {
        #pragma unroll
        for (int ni = 0; ni < 3; ++ni) {
            int col = n0 + ni * 16 + lr;
            float sc = (col < 64) ? SCALE : 1.0f;
            #pragma unroll
            for (int r = 0; r < 4; ++r) {
                int row = mi * 16 + lk * 4 + r;
                lds[row * OS_STRIDE + col] = f2bf(acc[mi][ni][r] * sc);
            }
        }
    }
    __syncthreads();

    // q,k (cols 0..127) -> qk[BT][128], coalesced
    #pragma unroll
    for (int p = 0; p < 4; ++p) {
        int i = p * 256 + tid;
        int row = i >> 4, c = i & 15;
        *(uint4*)&qk[(size_t)(m0 + row) * 128 + c * 8] =
            *(const uint4*)&lds[row * OS_STRIDE + c * 8];
    }
    // v (cols 128..191) transposed -> vtg[b][h][t]
    const int bb = m0 >> 8, tloc = m0 & 255;
    #pragma unroll
    for (int p = 0; p < 2; ++p) {
        int j = p * 256 + tid;
        int h = j >> 3, tc = j & 7;
        unsigned short tmp[8];
        #pragma unroll
        for (int tt = 0; tt < 8; ++tt)
            tmp[tt] = lds[(tc * 8 + tt) * OS_STRIDE + 128 + h];
        *(uint4*)&vtg[(size_t)bb * 16384 + h * 256 + tloc + tc * 8] = *(uint4*)tmp;
    }
}

// ---------------- kernel 2: MFMA flash attention ----------------
// grid 512 (one block per batch), block 256 (4 waves).
__global__ __launch_bounds__(256) void attn(
    const unsigned short* __restrict__ qk,
    const unsigned short* __restrict__ vtg,
    float* __restrict__ out)
{
    __shared__ __align__(16) unsigned short vtl[64 * 256];   // V^T swizzled, 32 KB
    __shared__ __align__(16) unsigned short plds[4 * 2048];  // per-wave P, 16 KB

    const int b = blockIdx.x, tid = threadIdx.x;
    const int w = tid >> 6, lane = tid & 63;
    const int lr = lane & 15, lk = lane >> 4;

    // stage V^T with XOR swizzle: vtl[h][t ^ ((h&7)<<3)]
    const uint4* vsrc = (const uint4*)(vtg + (size_t)b * 16384);
    #pragma unroll
    for (int p = 0; p < 8; ++p) {
        int i = p * 256 + tid, h = i >> 5, cc = i & 31;
        *(uint4*)&vtl[h * 256 + ((cc * 8) ^ ((h & 7) << 3))] = vsrc[i];
    }

    const int q0a[2]  = {32 * w, 224 - 32 * w};
    const int last[2] = {w >> 1, (255 - 32 * w) >> 6};   // last[1] >= last[0]

    // Q A-frags (pre-scaled at projection): [strip][mi][kc]
    bf16x8 qa[2][2][2];
    #pragma unroll
    for (int s2 = 0; s2 < 2; ++s2)
        #pragma unroll
        for (int mi = 0; mi < 2; ++mi)
            #pragma unroll
            for (int kc = 0; kc < 2; ++kc)
                qa[s2][mi][kc] = *(const bf16x8*)
                    &qk[((size_t)b * 256 + q0a[s2] + mi * 16 + lr) * 128 + kc * 32 + lk * 8];

    __syncthreads();

    f32x4 oacc[2][2][4];
    float mrow[2][2][4], lpart[2][2][4];
    #pragma unroll
    for (int s2 = 0; s2 < 2; ++s2)
        #pragma unroll
        for (int mi = 0; mi < 2; ++mi) {
            #pragma unroll
            for (int nh = 0; nh < 4; ++nh) oacc[s2][mi][nh] = (f32x4){0.f, 0.f, 0.f, 0.f};
            #pragma unroll
            for (int r = 0; r < 4; ++r) { mrow[s2][mi][r] = -INFINITY; lpart[s2][mi][r] = 0.f; }
        }

    unsigned short* pb = &plds[w * 2048];

    for (int st = 0; st <= last[1]; ++st) {
        // K B-frags for this s-tile (shared by both strips)
        bf16x8 kb[4][2];
        #pragma unroll
        for (int ni = 0; ni < 4; ++ni)
            #pragma unroll
            for (int kc = 0; kc < 2; ++kc)
                kb[ni][kc] = *(const bf16x8*)
                    &qk[((size_t)b * 256 + st * 64 + ni * 16 + lr) * 128 + 64 + kc * 32 + lk * 8];

        #pragma unroll
        for (int s2 = 0; s2 < 2; ++s2) {
            if (st > last[s2]) continue;
            const int q0 = q0a[s2];

            // S = Q K^T  (A=Q, B=K): D[q][s], col=lane&15=s, row=(lane>>4)*4+r=q
            f32x4 sa[2][4];
            #pragma unroll
            for (int mi = 0; mi < 2; ++mi)
                #pragma unroll
                for (int ni = 0; ni < 4; ++ni)
                    sa[mi][ni] = (f32x4){0.f, 0.f, 0.f, 0.f};
            #pragma unroll
            for (int mi = 0; mi < 2; ++mi)
                #pragma unroll
                for (int ni = 0; ni < 4; ++ni)
                    #pragma unroll
                    for (int kc = 0; kc < 2; ++kc)
                        sa[mi][ni] = __builtin_amdgcn_mfma_f32_16x16x32_bf16(
                            qa[s2][mi][kc], kb[ni][kc], sa[mi][ni], 0, 0, 0);

            // causal mask on the diagonal tile
            if (st == last[s2]) {
                #pragma unroll
                for (int mi = 0; mi < 2; ++mi)
                    #pragma unroll
                    for (int ni = 0; ni < 4; ++ni) {
                        int sg = st * 64 + ni * 16 + lr;
                        #pragma unroll
                        for (int r = 0; r < 4; ++r) {
                            int qg = q0 + mi * 16 + lk * 4 + r;
                            if (sg > qg) sa[mi][ni][r] = -INFINITY;
                        }
                    }
            }

            // row max: over ni in-register, then over lr via shfl_xor
            float pm[2][4];
            #pragma unroll
            for (int mi = 0; mi < 2; ++mi)
                #pragma unroll
                for (int r = 0; r < 4; ++r) {
                    float v = fmaxf(fmaxf(sa[mi][0][r], sa[mi][1][r]),
                                    fmaxf(sa[mi][2][r], sa[mi][3][r]));
                    pm[mi][r] = v;
                }
            #pragma unroll
            for (int stp = 1; stp < 16; stp <<= 1)
                #pragma unroll
                for (int mi = 0; mi < 2; ++mi)
                    #pragma unroll
                    for (int r = 0; r < 4; ++r)
                        pm[mi][r] = fmaxf(pm[mi][r], __shfl_xor(pm[mi][r], stp));

            // online update + rescale
            float mnew[2][4];
            #pragma unroll
            for (int mi = 0; mi < 2; ++mi)
                #pragma unroll
                for (int r = 0; r < 4; ++r) {
                    float mn = fmaxf(mrow[s2][mi][r], pm[mi][r]);
                    float corr = __expf(mrow[s2][mi][r] - mn);  // exp(-inf)=0 first time
                    mrow[s2][mi][r] = mn;
                    mnew[mi][r] = mn;
                    lpart[s2][mi][r] *= corr;
                    #pragma unroll
                    for (int nh = 0; nh < 4; ++nh) oacc[s2][mi][nh][r] *= corr;
                }

            // P = exp(S - m), lane-partial l, pack bf16 -> swizzled LDS [q][s^((q&7)<<3)]
            #pragma unroll
            for (int mi = 0; mi < 2; ++mi)
                #pragma unroll
                for (int ni = 0; ni < 4; ++ni) {
                    int s = ni * 16 + lr;
                    #pragma unroll
                    for (int r = 0; r < 4; ++r) {
                        float p = __expf(sa[mi][ni][r] - mnew[mi][r]);
                        lpart[s2][mi][r] += p;
                        int q = mi * 16 + lk * 4 + r;
                        pb[q * 64 + (s ^ ((q & 7) << 3))] = f2bf(p);
                    }
                }

            // PV: A = P (from swizzled LDS), B = V^T (from swizzled LDS)
            bf16x8 pa[2][2];
            #pragma unroll
            for (int mi = 0; mi < 2; ++mi)
                #pragma unroll
                for (int kc = 0; kc < 2; ++kc)
                    pa[mi][kc] = *(const bf16x8*)
                        &pb[(mi * 16 + lr) * 64 + ((kc * 32 + lk * 8) ^ ((lr & 7) << 3))];
            #pragma unroll
            for (int nh = 0; nh < 4; ++nh)
                #pragma unroll
                for (int kc = 0; kc < 2; ++kc) {
                    bf16x8 vb = *(const bf16x8*)
                        &vtl[(nh * 16 + lr) * 256 +
                             ((st * 64 + kc * 32 + lk * 8) ^ ((lr & 7) << 3))];
                    #pragma unroll
                    for (int mi = 0; mi < 2; ++mi)
                        oacc[s2][mi][nh] = __builtin_amdgcn_mfma_f32_16x16x32_bf16(
                            pa[mi][kc], vb, oacc[s2][mi][nh], 0, 0, 0);
                }
        }
    }

    // finalize: reduce l over lr, normalize, store
    #pragma unroll
    for (int s2 = 0; s2 < 2; ++s2)
        #pragma unroll
        for (int mi = 0; mi < 2; ++mi) {
            float linv[4];
            #pragma unroll
            for (int r = 0; r < 4; ++r) {
                float l = lpart[s2][mi][r];
                #pragma unroll
                for (int stp = 1; stp < 16; stp <<= 1) l += __shfl_xor(l, stp);
                linv[r] = 1.0f / l;
            }
            #pragma unroll
            for (int nh = 0; nh < 4; ++nh)
                #pragma unroll
                for (int r = 0; r < 4; ++r) {
                    int row = b * 256 + q0a[s2] + mi * 16 + lk * 4 + r;
                    out[(size_t)row * 64 + nh * 16 + lr] = oacc[s2][mi][nh][r] * linv[r];
                }
        }
}

extern "C" void kernel_launch(void* const* d_in, const int* in_sizes, int n_in,
                              void* d_out, int out_size, void* d_ws, size_t ws_size,
                              hipStream_t stream)
{
    const float* x  = (const float*)d_in[0];
    const float* Wq = (const float*)d_in[1];
    const float* Wk = (const float*)d_in[2];
    const float* Wv = (const float*)d_in[3];
    unsigned short* qkp = (unsigned short*)d_ws;                  // [BT][128] = 33.55 MB
    unsigned short* vtg = (unsigned short*)d_ws + (size_t)BT * 128;  // [512][64][256] = 16.78 MB
    unsigned short* bt  = (unsigned short*)d_out;                 // scratch, overwritten by attn
    float* out = (float*)d_out;

    prep_bt<<<(NQKV * CDIM + 255) / 256, 256, 0, stream>>>(Wq, Wk, Wv, bt);
    qkv_gemm<<<BT / 64, 256, 0, stream>>>(x, bt, qkp, vtg);
    attn<<<BSZ, 256, 0, stream>>>(qkp, vtg, out);
}

// Round 4
// 109.770 us; speedup vs baseline: 4.4683x; 1.0519x over previous
//
#include <hip/hip_runtime.h>
#include <hip/hip_bf16.h>

// B=512, T=256, C=384, H=64 single-head causal attention.
// Round 3: pipelined qkv_gemm.
//   prep_bt : W -> Bt[192][384] bf16 (in d_out scratch, overwritten later)
//   qkv_gemm: BK=128 double-buffered reg-staged pipeline, 34.8 KB LDS
//             (4 blocks/CU). q,k -> qk[BT][128] via LDS relayout (buf1 reuse);
//             v -> vtg[b][h][t] via direct uint2 stores (D-frag rows are
//             contiguous in t). q pre-scaled by 384^-0.5.
//   attn    : unchanged MFMA flash kernel from round 2.

constexpr int BSZ  = 512;
constexpr int TT   = 256;
constexpr int CDIM = 384;
constexpr int HDIM = 64;
constexpr int NQKV = 192;
constexpr long long BT = (long long)BSZ * TT;   // 131072 rows
constexpr float SCALE = 0.051031036307982884f;  // 384^-0.5 (C, not head size)

typedef __attribute__((ext_vector_type(8))) short bf16x8;
typedef __attribute__((ext_vector_type(4))) float f32x4;

__device__ inline unsigned short f2bf(float f) {
    __hip_bfloat16 h = __float2bfloat16(f);
    return *(unsigned short*)&h;
}
__device__ inline void unpack2(unsigned int u, float &a, float &b) {
    a = __uint_as_float(u << 16);
    b = __uint_as_float(u & 0xFFFF0000u);
}

// ---------------- kernel 0: Bt[192][384] bf16 = [Wq|Wk|Wv]^T ----------------
__global__ __launch_bounds__(256) void prep_bt(
    const float* __restrict__ Wq, const float* __restrict__ Wk,
    const float* __restrict__ Wv, unsigned short* __restrict__ bt)
{
    int idx = blockIdx.x * 256 + threadIdx.x;
    if (idx >= NQKV * CDIM) return;
    int n = idx / CDIM, k = idx - n * CDIM;
    const float* W = (n < 64) ? Wq : (n < 128) ? Wk : Wv;
    bt[idx] = f2bf(W[(size_t)k * HDIM + (n & 63)]);
}

// ---------------- kernel 1: pipelined QKV MFMA GEMM ----------------
// grid 2048 (M/64), block 256 (4 waves). Block tile 64x192, wave 64x48.
// K = 384 = 3 chunks x BK=128. LDS: 2 x [64][136] bf16 = 34,816 B.
constexpr int AST = 136;   // chunk stride: 272 B/row == 4 banks mod 32 -> 2-way max

__global__ __launch_bounds__(256, 4) void qkv_gemm(
    const float* __restrict__ x, const unsigned short* __restrict__ bt,
    unsigned short* __restrict__ qk, unsigned short* __restrict__ vtg)
{
    __shared__ __align__(16) unsigned short As[2][64 * AST];

    const int tid  = threadIdx.x;
    const int m0   = blockIdx.x * 64;
    const int wave = tid >> 6;
    const int lane = tid & 63;
    const int lr   = lane & 15;
    const int lk   = lane >> 4;
    const int n0   = wave * 48;

    const int srow = tid >> 5;        // staging: row (2 rows per pass of 256 thr? no:)
    const int sc4  = tid & 31;        // 32 float4 per 128-float chunk row

    float4 ld[8];

    // ---- load chunk 0 ----
    #pragma unroll
    for (int p = 0; p < 8; ++p) {
        int row = p * 8 + srow;
        ld[p] = *(const float4*)&x[(size_t)(m0 + row) * CDIM + 0 * 128 + sc4 * 4];
    }
    #pragma unroll
    for (int p = 0; p < 8; ++p) {
        int row = p * 8 + srow;
        unsigned short pk[4] = { f2bf(ld[p].x), f2bf(ld[p].y), f2bf(ld[p].z), f2bf(ld[p].w) };
        *(uint2*)&As[0][row * AST + sc4 * 4] = *(uint2*)pk;
    }
    __syncthreads();

    f32x4 acc[4][3];
    #pragma unroll
    for (int mi = 0; mi < 4; ++mi)
        #pragma unroll
        for (int ni = 0; ni < 3; ++ni)
            acc[mi][ni] = (f32x4){0.f, 0.f, 0.f, 0.f};

    #pragma unroll
    for (int c = 0; c < 3; ++c) {
        // issue next chunk's loads (overlap with MFMA below)
        if (c < 2) {
            #pragma unroll
            for (int p = 0; p < 8; ++p) {
                int row = p * 8 + srow;
                ld[p] = *(const float4*)&x[(size_t)(m0 + row) * CDIM + (c + 1) * 128 + sc4 * 4];
            }
        }
        // MFMA on buffer c&1: 4 K-steps of 32
        const unsigned short* buf = As[c & 1];
        #pragma unroll
        for (int ks = 0; ks < 4; ++ks) {
            bf16x8 a[4], b[3];
            #pragma unroll
            for (int mi = 0; mi < 4; ++mi)
                a[mi] = *(const bf16x8*)&buf[(mi * 16 + lr) * AST + ks * 32 + lk * 8];
            #pragma unroll
            for (int ni = 0; ni < 3; ++ni)
                b[ni] = *(const bf16x8*)
                    &bt[(size_t)(n0 + ni * 16 + lr) * CDIM + c * 128 + ks * 32 + lk * 8];
            #pragma unroll
            for (int mi = 0; mi < 4; ++mi)
                #pragma unroll
                for (int ni = 0; ni < 3; ++ni)
                    acc[mi][ni] = __builtin_amdgcn_mfma_f32_16x16x32_bf16(
                        a[mi], b[ni], acc[mi][ni], 0, 0, 0);
        }
        // convert + write next buffer
        if (c < 2) {
            #pragma unroll
            for (int p = 0; p < 8; ++p) {
                int row = p * 8 + srow;
                unsigned short pk[4] = { f2bf(ld[p].x), f2bf(ld[p].y), f2bf(ld[p].z), f2bf(ld[p].w) };
                *(uint2*)&As[(c + 1) & 1][row * AST + sc4 * 4] = *(uint2*)pk;
            }
            __syncthreads();
        }
    }

    // ---- epilogue ----
    // v cols (>=128): D-frag rows are 4 consecutive t -> direct uint2 stores
    const int bb = m0 >> 8, tloc = m0 & 255;
    #pragma unroll
    for (int ni = 0; ni < 3; ++ni) {
        int col0 = n0 + ni * 16;
        if (col0 >= 128) {
            int h = col0 - 128 + lr;
            #pragma unroll
            for (int mi = 0; mi < 4; ++mi) {
                unsigned short pk[4];
                #pragma unroll
                for (int r = 0; r < 4; ++r) pk[r] = f2bf(acc[mi][ni][r]);
                *(uint2*)&vtg[(size_t)bb * 16384 + h * 256 + tloc + mi * 16 + lk * 4] =
                    *(uint2*)pk;
            }
        }
    }
    // q,k cols (<128): relayout through As[1] (free: chunk 2 read As[0] only)
    #pragma unroll
    for (int ni = 0; ni < 3; ++ni) {
        int col = n0 + ni * 16 + lr;
        if (col < 128) {
            float sc = (col < 64) ? SCALE : 1.0f;
            #pragma unroll
            for (int mi = 0; mi < 4; ++mi)
                #pragma unroll
                for (int r = 0; r < 4; ++r)
                    As[1][(mi * 16 + lk * 4 + r) * AST + col] = f2bf(acc[mi][ni][r] * sc);
        }
    }
    __syncthreads();
    #pragma unroll
    for (int p = 0; p < 4; ++p) {
        int i = p * 256 + tid;          // 1024 uint4 = 64 rows x 16
        int row = i >> 4, cc = i & 15;
        *(uint4*)&qk[(size_t)(m0 + row) * 128 + cc * 8] =
            *(const uint4*)&As[1][row * AST + cc * 8];
    }
}

// ---------------- kernel 2: MFMA flash attention (unchanged) ----------------
__global__ __launch_bounds__(256) void attn(
    const unsigned short* __restrict__ qk,
    const unsigned short* __restrict__ vtg,
    float* __restrict__ out)
{
    __shared__ __align__(16) unsigned short vtl[64 * 256];   // V^T swizzled, 32 KB
    __shared__ __align__(16) unsigned short plds[4 * 2048];  // per-wave P, 16 KB

    const int b = blockIdx.x, tid = threadIdx.x;
    const int w = tid >> 6, lane = tid & 63;
    const int lr = lane & 15, lk = lane >> 4;

    const uint4* vsrc = (const uint4*)(vtg + (size_t)b * 16384);
    #pragma unroll
    for (int p = 0; p < 8; ++p) {
        int i = p * 256 + tid, h = i >> 5, cc = i & 31;
        *(uint4*)&vtl[h * 256 + ((cc * 8) ^ ((h & 7) << 3))] = vsrc[i];
    }

    const int q0a[2]  = {32 * w, 224 - 32 * w};
    const int last[2] = {w >> 1, (255 - 32 * w) >> 6};

    bf16x8 qa[2][2][2];
    #pragma unroll
    for (int s2 = 0; s2 < 2; ++s2)
        #pragma unroll
        for (int mi = 0; mi < 2; ++mi)
            #pragma unroll
            for (int kc = 0; kc < 2; ++kc)
                qa[s2][mi][kc] = *(const bf16x8*)
                    &qk[((size_t)b * 256 + q0a[s2] + mi * 16 + lr) * 128 + kc * 32 + lk * 8];

    __syncthreads();

    f32x4 oacc[2][2][4];
    float mrow[2][2][4], lpart[2][2][4];
    #pragma unroll
    for (int s2 = 0; s2 < 2; ++s2)
        #pragma unroll
        for (int mi = 0; mi < 2; ++mi) {
            #pragma unroll
            for (int nh = 0; nh < 4; ++nh) oacc[s2][mi][nh] = (f32x4){0.f, 0.f, 0.f, 0.f};
            #pragma unroll
            for (int r = 0; r < 4; ++r) { mrow[s2][mi][r] = -INFINITY; lpart[s2][mi][r] = 0.f; }
        }

    unsigned short* pb = &plds[w * 2048];

    for (int st = 0; st <= last[1]; ++st) {
        bf16x8 kb[4][2];
        #pragma unroll
        for (int ni = 0; ni < 4; ++ni)
            #pragma unroll
            for (int kc = 0; kc < 2; ++kc)
                kb[ni][kc] = *(const bf16x8*)
                    &qk[((size_t)b * 256 + st * 64 + ni * 16 + lr) * 128 + 64 + kc * 32 + lk * 8];

        #pragma unroll
        for (int s2 = 0; s2 < 2; ++s2) {
            if (st > last[s2]) continue;
            const int q0 = q0a[s2];

            f32x4 sa[2][4];
            #pragma unroll
            for (int mi = 0; mi < 2; ++mi)
                #pragma unroll
                for (int ni = 0; ni < 4; ++ni)
                    sa[mi][ni] = (f32x4){0.f, 0.f, 0.f, 0.f};
            #pragma unroll
            for (int mi = 0; mi < 2; ++mi)
                #pragma unroll
                for (int ni = 0; ni < 4; ++ni)
                    #pragma unroll
                    for (int kc = 0; kc < 2; ++kc)
                        sa[mi][ni] = __builtin_amdgcn_mfma_f32_16x16x32_bf16(
                            qa[s2][mi][kc], kb[ni][kc], sa[mi][ni], 0, 0, 0);

            if (st == last[s2]) {
                #pragma unroll
                for (int mi = 0; mi < 2; ++mi)
                    #pragma unroll
                    for (int ni = 0; ni < 4; ++ni) {
                        int sg = st * 64 + ni * 16 + lr;
                        #pragma unroll
                        for (int r = 0; r < 4; ++r) {
                            int qg = q0 + mi * 16 + lk * 4 + r;
                            if (sg > qg) sa[mi][ni][r] = -INFINITY;
                        }
                    }
            }

            float pm[2][4];
            #pragma unroll
            for (int mi = 0; mi < 2; ++mi)
                #pragma unroll
                for (int r = 0; r < 4; ++r)
                    pm[mi][r] = fmaxf(fmaxf(sa[mi][0][r], sa[mi][1][r]),
                                      fmaxf(sa[mi][2][r], sa[mi][3][r]));
            #pragma unroll
            for (int stp = 1; stp < 16; stp <<= 1)
                #pragma unroll
                for (int mi = 0; mi < 2; ++mi)
                    #pragma unroll
                    for (int r = 0; r < 4; ++r)
                        pm[mi][r] = fmaxf(pm[mi][r], __shfl_xor(pm[mi][r], stp));

            float mnew[2][4];
            #pragma unroll
            for (int mi = 0; mi < 2; ++mi)
                #pragma unroll
                for (int r = 0; r < 4; ++r) {
                    float mn = fmaxf(mrow[s2][mi][r], pm[mi][r]);
                    float corr = __expf(mrow[s2][mi][r] - mn);
                    mrow[s2][mi][r] = mn;
                    mnew[mi][r] = mn;
                    lpart[s2][mi][r] *= corr;
                    #pragma unroll
                    for (int nh = 0; nh < 4; ++nh) oacc[s2][mi][nh][r] *= corr;
                }

            #pragma unroll
            for (int mi = 0; mi < 2; ++mi)
                #pragma unroll
                for (int ni = 0; ni < 4; ++ni) {
                    int s = ni * 16 + lr;
                    #pragma unroll
                    for (int r = 0; r < 4; ++r) {
                        float p = __expf(sa[mi][ni][r] - mnew[mi][r]);
                        lpart[s2][mi][r] += p;
                        int q = mi * 16 + lk * 4 + r;
                        pb[q * 64 + (s ^ ((q & 7) << 3))] = f2bf(p);
                    }
                }

            bf16x8 pa[2][2];
            #pragma unroll
            for (int mi = 0; mi < 2; ++mi)
                #pragma unroll
                for (int kc = 0; kc < 2; ++kc)
                    pa[mi][kc] = *(const bf16x8*)
                        &pb[(mi * 16 + lr) * 64 + ((kc * 32 + lk * 8) ^ ((lr & 7) << 3))];
            #pragma unroll
            for (int nh = 0; nh < 4; ++nh)
                #pragma unroll
                for (int kc = 0; kc < 2; ++kc) {
                    bf16x8 vb = *(const bf16x8*)
                        &vtl[(nh * 16 + lr) * 256 +
                             ((st * 64 + kc * 32 + lk * 8) ^ ((lr & 7) << 3))];
                    #pragma unroll
                    for (int mi = 0; mi < 2; ++mi)
                        oacc[s2][mi][nh] = __builtin_amdgcn_mfma_f32_16x16x32_bf16(
                            pa[mi][kc], vb, oacc[s2][mi][nh], 0, 0, 0);
                }
        }
    }

    #pragma unroll
    for (int s2 = 0; s2 < 2; ++s2)
        #pragma unroll
        for (int mi = 0; mi < 2; ++mi) {
            float linv[4];
            #pragma unroll
            for (int r = 0; r < 4; ++r) {
                float l = lpart[s2][mi][r];
                #pragma unroll
                for (int stp = 1; stp < 16; stp <<= 1) l += __shfl_xor(l, stp);
                linv[r] = 1.0f / l;
            }
            #pragma unroll
            for (int nh = 0; nh < 4; ++nh)
                #pragma unroll
                for (int r = 0; r < 4; ++r) {
                    int row = b * 256 + q0a[s2] + mi * 16 + lk * 4 + r;
                    out[(size_t)row * 64 + nh * 16 + lr] = oacc[s2][mi][nh][r] * linv[r];
                }
        }
}

extern "C" void kernel_launch(void* const* d_in, const int* in_sizes, int n_in,
                              void* d_out, int out_size, void* d_ws, size_t ws_size,
                              hipStream_t stream)
{
    const float* x  = (const float*)d_in[0];
    const float* Wq = (const float*)d_in[1];
    const float* Wk = (const float*)d_in[2];
    const float* Wv = (const float*)d_in[3];
    unsigned short* qkp = (unsigned short*)d_ws;                     // [BT][128] = 33.55 MB
    unsigned short* vtg = (unsigned short*)d_ws + (size_t)BT * 128;  // [512][64][256] = 16.78 MB
    unsigned short* bt  = (unsigned short*)d_out;                    // scratch, overwritten by attn
    float* out = (float*)d_out;

    prep_bt<<<(NQKV * CDIM + 255) / 256, 256, 0, stream>>>(Wq, Wk, Wv, bt);
    qkv_gemm<<<BT / 64, 256, 0, stream>>>(x, bt, qkp, vtg);
    attn<<<BSZ, 256, 0, stream>>>(qkp, vtg, out);
}

// Round 5
// 85.463 us; speedup vs baseline: 5.7391x; 1.2844x over previous
//
#include <hip/hip_runtime.h>
#include <hip/hip_bf16.h>

// B=512, T=256, C=384, H=64 single-head causal attention.
// Round 4: single fused kernel per batch.
//   prep_bt: W -> Bt[192][384] bf16 in ws.
//   fused  : grid 512 (one block per batch), 1024 threads (16 waves),
//            1 block/CU (136 KB LDS).
//     GEMM phase: qkv = x(256x384) @ Bt^T(384x192), BK=32 dbuf reg-staged;
//       wave (mg=w>>2, ng=w&3) owns 64x48 tile; acc[4][3].
//     Epilogue: D-frags -> LDS directly: q (xSCALE) + K into XOR-swizzled
//       [256][64]; V transposed into swizzled vt[64][256] (no HBM round trip).
//     Attn phase: wave w owns q rows [16w,16w+16); tiles st=0..w>>2
//       (per-SIMD balanced: {1,2,3,4} per wave set). P via freed q region.

constexpr int BSZ  = 512;
constexpr int TT   = 256;
constexpr int CDIM = 384;
constexpr int HDIM = 64;
constexpr int NQKV = 192;
constexpr long long BT = (long long)BSZ * TT;
constexpr float SCALE = 0.051031036307982884f;  // 384^-0.5 (C, not head size)

typedef __attribute__((ext_vector_type(8))) short bf16x8;
typedef __attribute__((ext_vector_type(4))) float f32x4;

__device__ inline unsigned short f2bf(float f) {
    __hip_bfloat16 h = __float2bfloat16(f);
    return *(unsigned short*)&h;
}

// ---------------- kernel 0: Bt[192][384] bf16 = [Wq|Wk|Wv]^T ----------------
__global__ __launch_bounds__(256) void prep_bt(
    const float* __restrict__ Wq, const float* __restrict__ Wk,
    const float* __restrict__ Wv, unsigned short* __restrict__ bt)
{
    int idx = blockIdx.x * 256 + threadIdx.x;
    if (idx >= NQKV * CDIM) return;
    int n = idx / CDIM, k = idx - n * CDIM;
    const float* W = (n < 64) ? Wq : (n < 128) ? Wk : Wv;
    bt[idx] = f2bf(W[(size_t)k * HDIM + (n & 63)]);
}

// ---------------- fused QKV-projection + flash attention ----------------
constexpr int AST = 40;   // staging row stride (80 B: 16B-aligned, ~2-way banks)

__global__ __launch_bounds__(1024) void fused(
    const float* __restrict__ x, const unsigned short* __restrict__ bt,
    float* __restrict__ out)
{
    __shared__ __align__(16) unsigned short As[2][256 * AST];  // 40960 B
    __shared__ __align__(16) unsigned short qp[256 * 64];      // q, then P bufs
    __shared__ __align__(16) unsigned short kl[256 * 64];      // K swizzled
    __shared__ __align__(16) unsigned short vt[64 * 256];      // V^T swizzled

    const int b = blockIdx.x, tid = threadIdx.x;
    const int w = tid >> 6, lane = tid & 63;
    const int lr = lane & 15, lk = lane >> 4;
    const int mg = w >> 2, ng = w & 3;
    const int m0 = mg * 64, n0 = ng * 48;
    const float* xb = x + (size_t)b * TT * CDIM;

    const int srow = tid >> 3, sc4 = tid & 7;   // 128 rows/pass, 8 float4/row

    // ---- GEMM phase: load chunk 0 ----
    float4 ld0 = *(const float4*)&xb[(size_t)srow * CDIM + sc4 * 4];
    float4 ld1 = *(const float4*)&xb[(size_t)(128 + srow) * CDIM + sc4 * 4];
    {
        unsigned short p0[4] = { f2bf(ld0.x), f2bf(ld0.y), f2bf(ld0.z), f2bf(ld0.w) };
        unsigned short p1[4] = { f2bf(ld1.x), f2bf(ld1.y), f2bf(ld1.z), f2bf(ld1.w) };
        *(uint2*)&As[0][srow * AST + sc4 * 4] = *(uint2*)p0;
        *(uint2*)&As[0][(128 + srow) * AST + sc4 * 4] = *(uint2*)p1;
    }
    __syncthreads();

    f32x4 acc[4][3];
    #pragma unroll
    for (int mi = 0; mi < 4; ++mi)
        #pragma unroll
        for (int ni = 0; ni < 3; ++ni)
            acc[mi][ni] = (f32x4){0.f, 0.f, 0.f, 0.f};

    for (int ks = 0; ks < 12; ++ks) {
        if (ks < 11) {   // issue next chunk's loads (overlap with MFMA)
            ld0 = *(const float4*)&xb[(size_t)srow * CDIM + (ks + 1) * 32 + sc4 * 4];
            ld1 = *(const float4*)&xb[(size_t)(128 + srow) * CDIM + (ks + 1) * 32 + sc4 * 4];
        }
        const unsigned short* buf = &As[ks & 1][0];
        bf16x8 a[4], bb[3];
        #pragma unroll
        for (int mi = 0; mi < 4; ++mi)
            a[mi] = *(const bf16x8*)&buf[(m0 + mi * 16 + lr) * AST + lk * 8];
        #pragma unroll
        for (int ni = 0; ni < 3; ++ni)
            bb[ni] = *(const bf16x8*)&bt[(size_t)(n0 + ni * 16 + lr) * CDIM + ks * 32 + lk * 8];
        #pragma unroll
        for (int mi = 0; mi < 4; ++mi)
            #pragma unroll
            for (int ni = 0; ni < 3; ++ni)
                acc[mi][ni] = __builtin_amdgcn_mfma_f32_16x16x32_bf16(
                    a[mi], bb[ni], acc[mi][ni], 0, 0, 0);
        if (ks < 11) {   // convert + write next buffer
            unsigned short p0[4] = { f2bf(ld0.x), f2bf(ld0.y), f2bf(ld0.z), f2bf(ld0.w) };
            unsigned short p1[4] = { f2bf(ld1.x), f2bf(ld1.y), f2bf(ld1.z), f2bf(ld1.w) };
            unsigned short* nb = &As[(ks + 1) & 1][0];
            *(uint2*)&nb[srow * AST + sc4 * 4] = *(uint2*)p0;
            *(uint2*)&nb[(128 + srow) * AST + sc4 * 4] = *(uint2*)p1;
            __syncthreads();
        }
    }

    // ---- epilogue: route D-frags into LDS homes ----
    // D-layout: col = n0+ni*16+lr, row = m0+mi*16+lk*4+r
    #pragma unroll
    for (int ni = 0; ni < 3; ++ni) {
        const int col0 = n0 + ni * 16;
        const int col  = col0 + lr;
        if (col0 < 64) {              // q: pre-scale, swizzled [256][64]
            #pragma unroll
            for (int mi = 0; mi < 4; ++mi)
                #pragma unroll
                for (int r = 0; r < 4; ++r) {
                    int row = m0 + mi * 16 + lk * 4 + r;
                    qp[row * 64 + (col ^ ((row & 7) << 3))] = f2bf(acc[mi][ni][r] * SCALE);
                }
        } else if (col0 < 128) {      // k: swizzled [256][64]
            int c2 = col - 64;
            #pragma unroll
            for (int mi = 0; mi < 4; ++mi)
                #pragma unroll
                for (int r = 0; r < 4; ++r) {
                    int row = m0 + mi * 16 + lk * 4 + r;
                    kl[row * 64 + (c2 ^ ((row & 7) << 3))] = f2bf(acc[mi][ni][r]);
                }
        } else {                      // v: transpose -> vt[h][t] swizzled
            int h = col - 128;
            #pragma unroll
            for (int mi = 0; mi < 4; ++mi) {
                int t0 = m0 + mi * 16 + lk * 4;
                unsigned short pk[4];
                #pragma unroll
                for (int r = 0; r < 4; ++r) pk[r] = f2bf(acc[mi][ni][r]);
                *(uint2*)&vt[h * 256 + (t0 ^ ((h & 7) << 3))] = *(uint2*)pk;
            }
        }
    }
    __syncthreads();

    // ---- attention phase ----
    const int q0 = 16 * w;
    bf16x8 qa[2];
    #pragma unroll
    for (int kc = 0; kc < 2; ++kc)
        qa[kc] = *(const bf16x8*)
            &qp[(q0 + lr) * 64 + ((kc * 32 + lk * 8) ^ ((lr & 7) << 3))];
    __syncthreads();   // all Q reads done before P overwrites qp

    unsigned short* pb = &qp[w * 1024];   // 16 rows x 64 per wave

    f32x4 oacc[4];
    float mrow[4], lpart[4];
    #pragma unroll
    for (int nh = 0; nh < 4; ++nh) oacc[nh] = (f32x4){0.f, 0.f, 0.f, 0.f};
    #pragma unroll
    for (int r = 0; r < 4; ++r) { mrow[r] = -INFINITY; lpart[r] = 0.f; }

    const int lastt = w >> 2;
    for (int st = 0; st <= lastt; ++st) {
        // S = Q K^T
        f32x4 sa[4];
        #pragma unroll
        for (int ni = 0; ni < 4; ++ni) sa[ni] = (f32x4){0.f, 0.f, 0.f, 0.f};
        #pragma unroll
        for (int ni = 0; ni < 4; ++ni) {
            int row = st * 64 + ni * 16 + lr;
            #pragma unroll
            for (int kc = 0; kc < 2; ++kc) {
                bf16x8 kb = *(const bf16x8*)
                    &kl[row * 64 + ((kc * 32 + lk * 8) ^ ((lr & 7) << 3))];
                sa[ni] = __builtin_amdgcn_mfma_f32_16x16x32_bf16(qa[kc], kb, sa[ni], 0, 0, 0);
            }
        }
        // causal mask (diagonal tile only)
        if (st == lastt) {
            #pragma unroll
            for (int ni = 0; ni < 4; ++ni) {
                int sg = st * 64 + ni * 16 + lr;
                #pragma unroll
                for (int r = 0; r < 4; ++r) {
                    int qg = q0 + lk * 4 + r;
                    if (sg > qg) sa[ni][r] = -INFINITY;
                }
            }
        }
        // row max over ni, then over lr
        float pm[4];
        #pragma unroll
        for (int r = 0; r < 4; ++r)
            pm[r] = fmaxf(fmaxf(sa[0][r], sa[1][r]), fmaxf(sa[2][r], sa[3][r]));
        #pragma unroll
        for (int stp = 1; stp < 16; stp <<= 1)
            #pragma unroll
            for (int r = 0; r < 4; ++r)
                pm[r] = fmaxf(pm[r], __shfl_xor(pm[r], stp));
        // online update
        float mnew[4];
        #pragma unroll
        for (int r = 0; r < 4; ++r) {
            float mn = fmaxf(mrow[r], pm[r]);
            float corr = __expf(mrow[r] - mn);   // exp(-inf)=0 first time
            mrow[r] = mn; mnew[r] = mn;
            lpart[r] *= corr;
            #pragma unroll
            for (int nh = 0; nh < 4; ++nh) oacc[nh][r] *= corr;
        }
        // P = exp(S-m) -> swizzled per-wave LDS
        #pragma unroll
        for (int ni = 0; ni < 4; ++ni) {
            int s = ni * 16 + lr;
            #pragma unroll
            for (int r = 0; r < 4; ++r) {
                float p = __expf(sa[ni][r] - mnew[r]);
                lpart[r] += p;
                int qr = lk * 4 + r;
                pb[qr * 64 + (s ^ ((qr & 7) << 3))] = f2bf(p);
            }
        }
        // PV
        bf16x8 pa[2];
        #pragma unroll
        for (int kc = 0; kc < 2; ++kc)
            pa[kc] = *(const bf16x8*)
                &pb[lr * 64 + ((kc * 32 + lk * 8) ^ ((lr & 7) << 3))];
        #pragma unroll
        for (int nh = 0; nh < 4; ++nh) {
            int hrow = nh * 16 + lr;
            #pragma unroll
            for (int kc = 0; kc < 2; ++kc) {
                bf16x8 vb = *(const bf16x8*)
                    &vt[hrow * 256 + ((st * 64 + kc * 32 + lk * 8) ^ ((hrow & 7) << 3))];
                oacc[nh] = __builtin_amdgcn_mfma_f32_16x16x32_bf16(pa[kc], vb, oacc[nh], 0, 0, 0);
            }
        }
    }

    // ---- finalize ----
    float linv[4];
    #pragma unroll
    for (int r = 0; r < 4; ++r) {
        float l = lpart[r];
        #pragma unroll
        for (int stp = 1; stp < 16; stp <<= 1) l += __shfl_xor(l, stp);
        linv[r] = 1.0f / l;
    }
    #pragma unroll
    for (int nh = 0; nh < 4; ++nh)
        #pragma unroll
        for (int r = 0; r < 4; ++r) {
            size_t row = (size_t)b * TT + q0 + lk * 4 + r;
            out[row * HDIM + nh * 16 + lr] = oacc[nh][r] * linv[r];
        }
}

extern "C" void kernel_launch(void* const* d_in, const int* in_sizes, int n_in,
                              void* d_out, int out_size, void* d_ws, size_t ws_size,
                              hipStream_t stream)
{
    const float* x  = (const float*)d_in[0];
    const float* Wq = (const float*)d_in[1];
    const float* Wk = (const float*)d_in[2];
    const float* Wv = (const float*)d_in[3];
    unsigned short* bt = (unsigned short*)d_ws;   // [192][384] bf16 = 147 KB
    float* out = (float*)d_out;

    prep_bt<<<(NQKV * CDIM + 255) / 256, 256, 0, stream>>>(Wq, Wk, Wv, bt);
    fused<<<BSZ, 1024, 0, stream>>>(x, bt, out);
}

// Round 6
// 64.956 us; speedup vs baseline: 7.5510x; 1.3157x over previous
//
#include <hip/hip_runtime.h>
#include <hip/hip_bf16.h>

// B=512, T=256, C=384, H=64 single-head causal attention.
// Round 5: barrier-free GEMM phase.
//   prep_bt: W -> Bt[192][384] bf16 in ws.
//   fused  : grid 512 (block = batch), 1024 threads (16 waves), 1 block/CU.
//     Stage Bt into LDS (padded [192][392], 147 KB, 2-way banks).
//     GEMM: wave w owns rows [16w,16w+16) x N=192; A-frags direct from
//       global x (1 chunk hand-rotated lookahead, NO barriers/LDS in loop);
//       B-frags ds_read_b128 from LDS Bt. acc[12] f32x4.
//     One barrier, then LDS is re-purposed (overlay): q -> wave-private
//       P-region (swizzled), K -> kl[256][64] swz, V -> vt[64][256] swz.
//     Attn: wave w q-rows [16w,16w+16), tiles st=0..w>>2 (SIMD-balanced),
//       online softmax, PV via MFMA. Same math as round 4.

constexpr int BSZ  = 512;
constexpr int TT   = 256;
constexpr int CDIM = 384;
constexpr int HDIM = 64;
constexpr int NQKV = 192;
constexpr float SCALE = 0.051031036307982884f;  // 384^-0.5 (C, not head size)
constexpr int BTST = 392;   // LDS Bt row stride in shorts: 784 B == 4 banks mod 32

typedef __attribute__((ext_vector_type(8))) short bf16x8;
typedef __attribute__((ext_vector_type(4))) float f32x4;

__device__ inline unsigned short f2bf(float f) {
    __hip_bfloat16 h = __float2bfloat16(f);
    return *(unsigned short*)&h;
}
__device__ inline bf16x8 pack8(float4 a, float4 b) {
    unsigned short p[8] = { f2bf(a.x), f2bf(a.y), f2bf(a.z), f2bf(a.w),
                            f2bf(b.x), f2bf(b.y), f2bf(b.z), f2bf(b.w) };
    return *(bf16x8*)p;
}

// ---------------- kernel 0: Bt[192][384] bf16 = [Wq|Wk|Wv]^T ----------------
__global__ __launch_bounds__(256) void prep_bt(
    const float* __restrict__ Wq, const float* __restrict__ Wk,
    const float* __restrict__ Wv, unsigned short* __restrict__ bt)
{
    int idx = blockIdx.x * 256 + threadIdx.x;
    if (idx >= NQKV * CDIM) return;
    int n = idx / CDIM, k = idx - n * CDIM;
    const float* W = (n < 64) ? Wq : (n < 128) ? Wk : Wv;
    bt[idx] = f2bf(W[(size_t)k * HDIM + (n & 63)]);
}

// ---------------- fused QKV-projection + flash attention ----------------
__global__ __launch_bounds__(1024) void fused(
    const float* __restrict__ x, const unsigned short* __restrict__ bt,
    float* __restrict__ out)
{
    // GEMM phase: smem = Bt [192][392]  (150,528 B)
    // attn phase (overlay): qs [16][1024] | kl [256][64] | vt [64][256]
    __shared__ __align__(16) unsigned short smem[NQKV * BTST];
    unsigned short* btl = smem;
    unsigned short* qs  = smem;           // 16384 shorts (q then P, wave-private)
    unsigned short* kl  = smem + 16384;   // 16384 shorts, K swizzled
    unsigned short* vt  = smem + 32768;   // 16384 shorts, V^T swizzled

    const int b = blockIdx.x, tid = threadIdx.x;
    const int w = tid >> 6, lane = tid & 63;
    const int lr = lane & 15, lk = lane >> 4;
    const float* xb = x + (size_t)b * TT * CDIM;

    // ---- stage Bt into LDS (9216 uint4, 9 per thread, coalesced) ----
    for (int i = tid; i < NQKV * CDIM / 8; i += 1024) {
        int row = i / 48, c8 = i - row * 48;
        *(uint4*)&btl[row * BTST + c8 * 8] = ((const uint4*)bt)[i];
    }
    __syncthreads();

    // ---- GEMM: wave w computes rows [16w,16w+16) x 192, K=384 ----
    const float* xrow = xb + (size_t)(16 * w + lr) * CDIM + lk * 8;

    f32x4 acc[12];
    #pragma unroll
    for (int ni = 0; ni < 12; ++ni) acc[ni] = (f32x4){0.f, 0.f, 0.f, 0.f};

    float4 f0 = *(const float4*)&xrow[0];
    float4 f1 = *(const float4*)&xrow[4];
    #pragma unroll 2
    for (int ks = 0; ks < 12; ++ks) {
        float4 c0 = f0, c1 = f1;
        if (ks < 11) {          // next chunk's loads issue before current use
            f0 = *(const float4*)&xrow[(ks + 1) * 32];
            f1 = *(const float4*)&xrow[(ks + 1) * 32 + 4];
        }
        bf16x8 a = pack8(c0, c1);
        #pragma unroll
        for (int ni = 0; ni < 12; ++ni) {
            bf16x8 bb = *(const bf16x8*)&btl[(ni * 16 + lr) * BTST + ks * 32 + lk * 8];
            acc[ni] = __builtin_amdgcn_mfma_f32_16x16x32_bf16(a, bb, acc[ni], 0, 0, 0);
        }
    }
    __syncthreads();   // all Bt reads done before LDS overlay writes

    // ---- epilogue: D-frags -> LDS homes. D: col=ni*16+lr, rowIn16=lk*4+r ----
    unsigned short* pq = qs + w * 1024;   // wave-private 16x64 (q, then P)
    #pragma unroll
    for (int ni = 0; ni < 4; ++ni)        // q: cols 0..63, pre-scaled
        #pragma unroll
        for (int r = 0; r < 4; ++r) {
            int qr = lk * 4 + r;
            int h  = ni * 16 + lr;
            pq[qr * 64 + (h ^ ((qr & 7) << 3))] = f2bf(acc[ni][r] * SCALE);
        }
    #pragma unroll
    for (int ni = 4; ni < 8; ++ni)        // k: cols 64..127 -> kl[t][h] swz
        #pragma unroll
        for (int r = 0; r < 4; ++r) {
            int row = 16 * w + lk * 4 + r;
            int c2  = (ni - 4) * 16 + lr;
            kl[row * 64 + (c2 ^ ((row & 7) << 3))] = f2bf(acc[ni][r]);
        }
    #pragma unroll
    for (int ni = 8; ni < 12; ++ni) {     // v: cols 128..191 -> vt[h][t] swz
        int h  = (ni - 8) * 16 + lr;
        int t0 = 16 * w + lk * 4;
        unsigned short pk[4];
        #pragma unroll
        for (int r = 0; r < 4; ++r) pk[r] = f2bf(acc[ni][r]);
        *(uint2*)&vt[h * 256 + (t0 ^ ((h & 7) << 3))] = *(uint2*)pk;
    }
    __syncthreads();

    // ---- attention: wave w owns q-rows [16w,16w+16) ----
    const int q0 = 16 * w;
    bf16x8 qa[2];
    #pragma unroll
    for (int kc = 0; kc < 2; ++kc)
        qa[kc] = *(const bf16x8*)&pq[lr * 64 + ((kc * 32 + lk * 8) ^ ((lr & 7) << 3))];
    // (qa read precedes P writes to same region — same wave, DS in-order)

    f32x4 oacc[4];
    float mrow[4], lpart[4];
    #pragma unroll
    for (int nh = 0; nh < 4; ++nh) oacc[nh] = (f32x4){0.f, 0.f, 0.f, 0.f};
    #pragma unroll
    for (int r = 0; r < 4; ++r) { mrow[r] = -INFINITY; lpart[r] = 0.f; }

    const int lastt = w >> 2;
    for (int st = 0; st <= lastt; ++st) {
        // S = Q K^T
        f32x4 sa[4];
        #pragma unroll
        for (int ni = 0; ni < 4; ++ni) sa[ni] = (f32x4){0.f, 0.f, 0.f, 0.f};
        #pragma unroll
        for (int ni = 0; ni < 4; ++ni) {
            int row = st * 64 + ni * 16 + lr;
            #pragma unroll
            for (int kc = 0; kc < 2; ++kc) {
                bf16x8 kb = *(const bf16x8*)
                    &kl[row * 64 + ((kc * 32 + lk * 8) ^ ((lr & 7) << 3))];
                sa[ni] = __builtin_amdgcn_mfma_f32_16x16x32_bf16(qa[kc], kb, sa[ni], 0, 0, 0);
            }
        }
        // causal mask (diagonal tile only)
        if (st == lastt) {
            #pragma unroll
            for (int ni = 0; ni < 4; ++ni) {
                int sg = st * 64 + ni * 16 + lr;
                #pragma unroll
                for (int r = 0; r < 4; ++r) {
                    int qg = q0 + lk * 4 + r;
                    if (sg > qg) sa[ni][r] = -INFINITY;
                }
            }
        }
        // row max over ni, then over lr
        float pm[4];
        #pragma unroll
        for (int r = 0; r < 4; ++r)
            pm[r] = fmaxf(fmaxf(sa[0][r], sa[1][r]), fmaxf(sa[2][r], sa[3][r]));
        #pragma unroll
        for (int stp = 1; stp < 16; stp <<= 1)
            #pragma unroll
            for (int r = 0; r < 4; ++r)
                pm[r] = fmaxf(pm[r], __shfl_xor(pm[r], stp));
        // online update
        float mnew[4];
        #pragma unroll
        for (int r = 0; r < 4; ++r) {
            float mn = fmaxf(mrow[r], pm[r]);
            float corr = __expf(mrow[r] - mn);   // exp(-inf)=0 first time
            mrow[r] = mn; mnew[r] = mn;
            lpart[r] *= corr;
            #pragma unroll
            for (int nh = 0; nh < 4; ++nh) oacc[nh][r] *= corr;
        }
        // P = exp(S-m) -> wave-private swizzled LDS
        #pragma unroll
        for (int ni = 0; ni < 4; ++ni) {
            int s = ni * 16 + lr;
            #pragma unroll
            for (int r = 0; r < 4; ++r) {
                float p = __expf(sa[ni][r] - mnew[r]);
                lpart[r] += p;
                int qr = lk * 4 + r;
                pq[qr * 64 + (s ^ ((qr & 7) << 3))] = f2bf(p);
            }
        }
        // PV
        bf16x8 pa[2];
        #pragma unroll
        for (int kc = 0; kc < 2; ++kc)
            pa[kc] = *(const bf16x8*)
                &pq[lr * 64 + ((kc * 32 + lk * 8) ^ ((lr & 7) << 3))];
        #pragma unroll
        for (int nh = 0; nh < 4; ++nh) {
            int hrow = nh * 16 + lr;
            #pragma unroll
            for (int kc = 0; kc < 2; ++kc) {
                bf16x8 vb = *(const bf16x8*)
                    &vt[hrow * 256 + ((st * 64 + kc * 32 + lk * 8) ^ ((hrow & 7) << 3))];
                oacc[nh] = __builtin_amdgcn_mfma_f32_16x16x32_bf16(pa[kc], vb, oacc[nh], 0, 0, 0);
            }
        }
    }

    // ---- finalize ----
    float linv[4];
    #pragma unroll
    for (int r = 0; r < 4; ++r) {
        float l = lpart[r];
        #pragma unroll
        for (int stp = 1; stp < 16; stp <<= 1) l += __shfl_xor(l, stp);
        linv[r] = 1.0f / l;
    }
    #pragma unroll
    for (int nh = 0; nh < 4; ++nh)
        #pragma unroll
        for (int r = 0; r < 4; ++r) {
            size_t row = (size_t)b * TT + q0 + lk * 4 + r;
            out[row * HDIM + nh * 16 + lr] = oacc[nh][r] * linv[r];
        }
}

extern "C" void kernel_launch(void* const* d_in, const int* in_sizes, int n_in,
                              void* d_out, int out_size, void* d_ws, size_t ws_size,
                              hipStream_t stream)
{
    const float* x  = (const float*)d_in[0];
    const float* Wq = (const float*)d_in[1];
    const float* Wk = (const float*)d_in[2];
    const float* Wv = (const float*)d_in[3];
    unsigned short* bt = (unsigned short*)d_ws;   // [192][384] bf16 = 147 KB
    float* out = (float*)d_out;

    prep_bt<<<(NQKV * CDIM + 255) / 256, 256, 0, stream>>>(Wq, Wk, Wv, bt);
    fused<<<BSZ, 1024, 0, stream>>>(x, bt, out);
}